// Round 1
// baseline (8567.143 us; speedup 1.0000x reference)
//
#include <hip/hip_runtime.h>
#include <math.h>

#define B_ 8
#define T_ 32
#define N_ 10000
#define F_ 16
#define E_ 160000
#define HG_ 64
#define HT_ 128
#define BT_ (B_*T_)
#define PB_ 157   // ceil(N/64) node-chunks per bt
#define EPS_ 1e-5f

// ---------------- CSR build ----------------
__global__ void k_zero(int* p, int n) {
  int i = blockIdx.x * 256 + threadIdx.x;
  if (i < n) p[i] = 0;
}

__global__ void k_deg(const int* __restrict__ dst, int* __restrict__ deg) {
  int e = blockIdx.x * 256 + threadIdx.x;
  if (e < E_) atomicAdd(&deg[dst[e]], 1);
}

__global__ void k_scan(const int* __restrict__ deg, int* __restrict__ row_ptr,
                       float* __restrict__ inv_deg) {
  __shared__ int part[256];
  int tid = threadIdx.x;
  int base = tid * 40;
  int s = 0;
  for (int i = 0; i < 40; i++) { int idx = base + i; if (idx < N_) s += deg[idx]; }
  part[tid] = s;
  __syncthreads();
  if (tid == 0) {
    int run = 0;
    for (int i = 0; i < 256; i++) { int v = part[i]; part[i] = run; run += v; }
  }
  __syncthreads();
  int run = part[tid];
  for (int i = 0; i < 40; i++) {
    int idx = base + i;
    if (idx < N_) {
      row_ptr[idx] = run;
      int d = deg[idx];
      run += d;
      inv_deg[idx] = 1.0f / fmaxf((float)d, 1.0f);
    } else if (idx == N_) {
      row_ptr[N_] = run;
    }
  }
}

__global__ void k_fill(const int* __restrict__ src, const int* __restrict__ dst,
                       const int* __restrict__ row_ptr, int* __restrict__ cursor,
                       int* __restrict__ col) {
  int e = blockIdx.x * 256 + threadIdx.x;
  if (e < E_) {
    int d = dst[e];
    int p = atomicAdd(&cursor[d], 1);
    col[row_ptr[d] + p] = src[e];
  }
}

// ---------------- SAGE layer 1 (F=16 -> HG=64), fused agg+matmul+LN+relu ----------------
// block = 256 thr = 4 waves; wave handles 16 nodes sequentially; lane = output feature j
__launch_bounds__(256, 4)
__global__ void k_sage1(const float* __restrict__ x, const int* __restrict__ row_ptr,
                        const int* __restrict__ col, const float* __restrict__ inv_deg,
                        const float* __restrict__ W1l, const float* __restrict__ b1,
                        const float* __restrict__ W1r, const float* __restrict__ g1,
                        const float* __restrict__ be1, float* __restrict__ h1,
                        int bt0, int CH, int swz) {
  __shared__ float aggL[4][16];
  __shared__ float selfL[4][16];
  int i = blockIdx.x;
  int btl, chunk;
  if (swz) {  // pin all blocks of one bt to one XCD (blockIdx%8 heuristic)
    int xcd = i & 7; int j = i >> 3; int per = CH >> 3;
    btl = xcd * per + j / PB_; chunk = j % PB_;
  } else {
    btl = i / PB_; chunk = i % PB_;
  }
  int bt = bt0 + btl;
  size_t xbase = (size_t)bt * (N_ * F_);
  int tid = threadIdx.x, wave = tid >> 6, lane = tid & 63;
  int f = lane & 15, eo = lane >> 4;

  // lane j keeps its weight rows in registers
  float4 wl[4], wr[4];
  const float4* Wl4 = (const float4*)(W1l + lane * 16);
  const float4* Wr4 = (const float4*)(W1r + lane * 16);
#pragma unroll
  for (int q = 0; q < 4; q++) { wl[q] = Wl4[q]; wr[q] = Wr4[q]; }
  float bj = b1[lane], gj = g1[lane], bej = be1[lane];

  for (int nn = 0; nn < 16; ++nn) {
    int n = chunk * 64 + wave * 16 + nn;
    bool ok = n < N_;
    float agg = 0.f, xs = 0.f;
    if (ok) {
      int s0 = row_ptr[n], s1 = row_ptr[n + 1];
      float acc = 0.f;
      for (int e = s0 + eo; e < s1; e += 4) {   // 4 edges x 16 feats per iter
        int s = col[e];
        acc += x[xbase + (size_t)s * F_ + f];
      }
      acc += __shfl_xor(acc, 16);
      acc += __shfl_xor(acc, 32);
      agg = acc * inv_deg[n];
      xs = x[xbase + (size_t)n * F_ + f];
      if (eo == 0) { aggL[wave][f] = agg; selfL[wave][f] = xs; }
    }
    __syncthreads();
    if (ok) {
      float hj = bj;
      const float4* a4 = (const float4*)aggL[wave];
      const float4* s4 = (const float4*)selfL[wave];
#pragma unroll
      for (int q = 0; q < 4; q++) {
        float4 av = a4[q], sv = s4[q];
        hj = fmaf(av.x, wl[q].x, hj); hj = fmaf(sv.x, wr[q].x, hj);
        hj = fmaf(av.y, wl[q].y, hj); hj = fmaf(sv.y, wr[q].y, hj);
        hj = fmaf(av.z, wl[q].z, hj); hj = fmaf(sv.z, wr[q].z, hj);
        hj = fmaf(av.w, wl[q].w, hj); hj = fmaf(sv.w, wr[q].w, hj);
      }
      // LayerNorm over the 64 lanes + relu
      float s = hj;
#pragma unroll
      for (int m = 1; m < 64; m <<= 1) s += __shfl_xor(s, m);
      float mu = s * (1.f / 64.f);
      float d = hj - mu;
      float v = d * d;
#pragma unroll
      for (int m = 1; m < 64; m <<= 1) v += __shfl_xor(v, m);
      float r = rsqrtf(v * (1.f / 64.f) + EPS_);
      float hv = fmaxf(d * r * gj + bej, 0.f);
      h1[((size_t)btl * N_ + n) * HG_ + lane] = hv;
    }
    __syncthreads();
  }
}

// ---------------- SAGE layer 2 (HG=64 -> HG=64) + mean-over-N partial ----------------
__launch_bounds__(256, 2)
__global__ void k_sage2(const float* __restrict__ h1, const int* __restrict__ row_ptr,
                        const int* __restrict__ col, const float* __restrict__ inv_deg,
                        const float* __restrict__ W2l, const float* __restrict__ b2,
                        const float* __restrict__ W2r, const float* __restrict__ g2,
                        const float* __restrict__ be2, float* __restrict__ Hsum,
                        int bt0, int CH, int swz) {
  __shared__ float aggL[4][64];
  __shared__ float selfL[4][64];
  __shared__ float sumL[4][64];
  int i = blockIdx.x;
  int btl, chunk;
  if (swz) {
    int xcd = i & 7; int j = i >> 3; int per = CH >> 3;
    btl = xcd * per + j / PB_; chunk = j % PB_;
  } else {
    btl = i / PB_; chunk = i % PB_;
  }
  int bt = bt0 + btl;
  int b = bt / T_, t = bt % T_;
  size_t hbase = (size_t)btl * (N_ * HG_);
  int tid = threadIdx.x, wave = tid >> 6, lane = tid & 63;

  // lane j holds W2l[j][0:64] and W2r[j][0:64] in registers (128 VGPRs)
  float4 wl[16], wr[16];
  const float4* Wl4 = (const float4*)(W2l + lane * 64);
  const float4* Wr4 = (const float4*)(W2r + lane * 64);
#pragma unroll
  for (int q = 0; q < 16; q++) { wl[q] = Wl4[q]; wr[q] = Wr4[q]; }
  float bj = b2[lane], gj = g2[lane], bej = be2[lane];
  float mysum = 0.f;

  for (int nn = 0; nn < 16; ++nn) {
    int n = chunk * 64 + wave * 16 + nn;
    bool ok = n < N_;
    if (ok) {
      int s0 = row_ptr[n], s1 = row_ptr[n + 1];
      float acc = 0.f;
      for (int e = s0; e < s1; ++e) {          // 64 contiguous floats per edge
        int s = col[e];
        acc += h1[hbase + (size_t)s * HG_ + lane];
      }
      aggL[wave][lane] = acc * inv_deg[n];
      selfL[wave][lane] = h1[hbase + (size_t)n * HG_ + lane];
    }
    __syncthreads();
    if (ok) {
      float hj = bj;
      const float4* a4 = (const float4*)aggL[wave];
      const float4* s4 = (const float4*)selfL[wave];
#pragma unroll
      for (int q = 0; q < 16; q++) {
        float4 av = a4[q], sv = s4[q];
        hj = fmaf(av.x, wl[q].x, hj); hj = fmaf(sv.x, wr[q].x, hj);
        hj = fmaf(av.y, wl[q].y, hj); hj = fmaf(sv.y, wr[q].y, hj);
        hj = fmaf(av.z, wl[q].z, hj); hj = fmaf(sv.z, wr[q].z, hj);
        hj = fmaf(av.w, wl[q].w, hj); hj = fmaf(sv.w, wr[q].w, hj);
      }
      float s = hj;
#pragma unroll
      for (int m = 1; m < 64; m <<= 1) s += __shfl_xor(s, m);
      float mu = s * (1.f / 64.f);
      float d = hj - mu;
      float v = d * d;
#pragma unroll
      for (int m = 1; m < 64; m <<= 1) v += __shfl_xor(v, m);
      float r = rsqrtf(v * (1.f / 64.f) + EPS_);
      float hv = fmaxf(d * r * gj + bej, 0.f);
      mysum += hv;
    }
    __syncthreads();
  }
  sumL[wave][lane] = mysum;
  __syncthreads();
  if (wave == 0) {
    float tot = sumL[0][lane] + sumL[1][lane] + sumL[2][lane] + sumL[3][lane];
    atomicAdd(&Hsum[(t * B_ + b) * HG_ + lane], tot);
  }
}

// ---------------- GRU input precompute: GI[t][b][384] (h-independent) ----------------
__global__ void k_gi(const float* __restrict__ Hsum, const float* __restrict__ W_ih,
                     const float* __restrict__ b_ih, float* __restrict__ GI) {
  __shared__ float xv[64];
  int tb = blockIdx.x;
  int tid = threadIdx.x;
  if (tid < 64) xv[tid] = Hsum[tb * 64 + tid] * (1.0f / (float)N_);
  __syncthreads();
  float g = b_ih[tid];
  const float4* W4 = (const float4*)(W_ih + tid * 64);
  const float4* x4 = (const float4*)xv;
#pragma unroll
  for (int q = 0; q < 16; q++) {
    float4 w = W4[q], xq = x4[q];
    g = fmaf(xq.x, w.x, g); g = fmaf(xq.y, w.y, g);
    g = fmaf(xq.z, w.z, g); g = fmaf(xq.w, w.w, g);
  }
  GI[tb * 384 + tid] = g;
}

// ---------------- sequential GRU + output head; one block per batch ----------------
__global__ void k_gru(const float* __restrict__ GI, const float* __restrict__ W_hh,
                      const float* __restrict__ b_hh, const float* __restrict__ Wh,
                      const float* __restrict__ bh, float* __restrict__ out) {
  __shared__ float hL[128];
  __shared__ float ghL[384];
  __shared__ float red[128];
  int b = blockIdx.x, tid = threadIdx.x;
  if (tid < 128) hL[tid] = 0.f;
  float bhh = b_hh[tid];
  const float4* W4 = (const float4*)(W_hh + tid * 128);
  for (int t = 0; t < T_; ++t) {
    __syncthreads();  // hL ready
    float g = bhh;
    const float4* h4 = (const float4*)hL;
#pragma unroll
    for (int q = 0; q < 32; q++) {
      float4 w = W4[q], hv = h4[q];
      g = fmaf(hv.x, w.x, g); g = fmaf(hv.y, w.y, g);
      g = fmaf(hv.z, w.z, g); g = fmaf(hv.w, w.w, g);
    }
    ghL[tid] = g;
    __syncthreads();
    float hnew = 0.f;
    if (tid < 128) {
      const float* gi = GI + (t * B_ + b) * 384;
      float rr = 1.f / (1.f + expf(-(gi[tid] + ghL[tid])));
      float zz = 1.f / (1.f + expf(-(gi[128 + tid] + ghL[128 + tid])));
      float nn = tanhf(gi[256 + tid] + rr * ghL[256 + tid]);
      hnew = (1.f - zz) * nn + zz * hL[tid];
    }
    __syncthreads();
    if (tid < 128) hL[tid] = hnew;
  }
  __syncthreads();
  if (tid < 128) red[tid] = hL[tid] * Wh[tid];
  __syncthreads();
  if (tid == 0) {
    float s = bh[0];
    for (int k = 0; k < 128; k++) s += red[k];
    out[b] = s;
  }
}

extern "C" void kernel_launch(void* const* d_in, const int* in_sizes, int n_in,
                              void* d_out, int out_size, void* d_ws, size_t ws_size,
                              hipStream_t stream) {
  const float* x    = (const float*)d_in[0];
  const int*   ei   = (const int*)d_in[1];
  const float* W1l  = (const float*)d_in[2];
  const float* b1   = (const float*)d_in[3];
  const float* W1r  = (const float*)d_in[4];
  const float* g1   = (const float*)d_in[5];
  const float* be1  = (const float*)d_in[6];
  const float* W2l  = (const float*)d_in[7];
  const float* b2   = (const float*)d_in[8];
  const float* W2r  = (const float*)d_in[9];
  const float* g2   = (const float*)d_in[10];
  const float* be2  = (const float*)d_in[11];
  const float* W_ih = (const float*)d_in[12];
  const float* W_hh = (const float*)d_in[13];
  const float* b_ih = (const float*)d_in[14];
  const float* b_hh = (const float*)d_in[15];
  const float* Wh   = (const float*)d_in[16];
  const float* bh   = (const float*)d_in[17];
  float* out = (float*)d_out;

  char* ws = (char*)d_ws;
  size_t off = 0;
  auto alloc = [&](size_t bytes) { void* p = ws + off; off += (bytes + 255) & ~(size_t)255; return p; };
  int*   deg     = (int*)alloc((size_t)N_ * 4);
  int*   row_ptr = (int*)alloc((size_t)(N_ + 1) * 4);
  int*   cursor  = (int*)alloc((size_t)N_ * 4);
  int*   col     = (int*)alloc((size_t)E_ * 4);
  float* ivd     = (float*)alloc((size_t)N_ * 4);
  float* Hsum    = (float*)alloc((size_t)BT_ * HG_ * 4);
  float* GI      = (float*)alloc((size_t)BT_ * 384 * 4);
  size_t fixed = off;
  float* h1 = (float*)(ws + off);

  size_t cap = (ws_size > fixed) ? (ws_size - fixed) / 4 : 0;
  int CH = (int)(cap / ((size_t)N_ * HG_));
  if (CH > BT_) CH = BT_;
  if (CH >= 8) CH &= ~7;   // multiple of 8 for XCD swizzle
  if (CH < 1) CH = 1;

  // zero deg/cursor/Hsum (whole fixed region, ~1.3 MB)
  int zn = (int)(fixed / 4);
  k_zero<<<(zn + 255) / 256, 256, 0, stream>>>((int*)ws, zn);

  const int* srcp = ei;
  const int* dstp = ei + E_;
  k_deg<<<(E_ + 255) / 256, 256, 0, stream>>>(dstp, deg);
  k_scan<<<1, 256, 0, stream>>>(deg, row_ptr, ivd);
  k_fill<<<(E_ + 255) / 256, 256, 0, stream>>>(srcp, dstp, row_ptr, cursor, col);

  for (int bt0 = 0; bt0 < BT_; bt0 += CH) {
    int c = BT_ - bt0 < CH ? BT_ - bt0 : CH;
    int swz = (c % 8 == 0) ? 1 : 0;
    k_sage1<<<c * PB_, 256, 0, stream>>>(x, row_ptr, col, ivd, W1l, b1, W1r, g1, be1,
                                         h1, bt0, c, swz);
    k_sage2<<<c * PB_, 256, 0, stream>>>(h1, row_ptr, col, ivd, W2l, b2, W2r, g2, be2,
                                         Hsum, bt0, c, swz);
  }
  k_gi<<<BT_, 384, 0, stream>>>(Hsum, W_ih, b_ih, GI);
  k_gru<<<B_, 384, 0, stream>>>(GI, W_hh, b_hh, Wh, bh, out);
}